// Round 6
// baseline (5724.398 us; speedup 1.0000x reference)
//
#include <hip/hip_runtime.h>
#include <hip/hip_bf16.h>

#define N_NODES 100000
#define N_EDGES 3200000
#define CH 128
#define NG 128
#define BN_EPS 1e-5f
#define NBUCK 1024   // bucket = dst >> 7 (128 nodes per bucket)
#define EPB 16384    // edges per k_bin block

using i32x4 = __attribute__((ext_vector_type(4))) int;
using u32x4 = __attribute__((ext_vector_type(4))) unsigned int;

__device__ __forceinline__ unsigned int packq(const float* v, float inv) {
    int q0 = __float2int_rn(v[0] * inv), q1 = __float2int_rn(v[1] * inv);
    int q2 = __float2int_rn(v[2] * inv), q3 = __float2int_rn(v[3] * inv);
    return (unsigned int)(q0 & 255) | ((unsigned int)(q1 & 255) << 8) |
           ((unsigned int)(q2 & 255) << 16) | ((unsigned int)(q3 & 255) << 24);
}

// ---------------- quantize x rows to int8 + per-row scale ----------------
__global__ __launch_bounds__(256) void k_quantx(const float* __restrict__ x,
                                                unsigned char* __restrict__ Xq,
                                                float* __restrict__ xs) {
    int t = threadIdx.x;
    int row = blockIdx.x * 16 + (t >> 4);
    int seg = t & 15;
    const float4* p = (const float4*)&x[(size_t)row * CH + seg * 8];
    float4 a = p[0], b = p[1];
    float v[8] = {a.x, a.y, a.z, a.w, b.x, b.y, b.z, b.w};
    float m = 0.f;
    #pragma unroll
    for (int i = 0; i < 8; ++i) m = fmaxf(m, fabsf(v[i]));
    m = fmaxf(m, __shfl_xor(m, 1, 64));
    m = fmaxf(m, __shfl_xor(m, 2, 64));
    m = fmaxf(m, __shfl_xor(m, 4, 64));
    m = fmaxf(m, __shfl_xor(m, 8, 64));
    float inv = (m > 0.f) ? 127.0f / m : 0.f;
    uint2 pk;
    pk.x = packq(&v[0], inv);
    pk.y = packq(&v[4], inv);
    *(uint2*)&Xq[(size_t)row * CH + seg * 8] = pk;
    if (seg == 0) xs[row] = m * (1.0f / 127.0f);
}

// ---------------- quantize W1/W2 per column (transposed) + BN fold ----------------
__global__ __launch_bounds__(256) void k_prepW(
    const float* __restrict__ W1, const float* __restrict__ W2,
    const float* __restrict__ gamma, const float* __restrict__ beta,
    const float* __restrict__ rmean, const float* __restrict__ rvar, const float* __restrict__ b1,
    unsigned char* __restrict__ Wq1T, float* __restrict__ wcs1,
    unsigned char* __restrict__ Wq2T, float* __restrict__ wcs2,
    float* __restrict__ A1, float* __restrict__ B1) {
    int t = threadIdx.x;
    const float* W = (t < 128) ? W1 : W2;
    unsigned char* WT = (t < 128) ? Wq1T : Wq2T;
    float* wcs = (t < 128) ? wcs1 : wcs2;
    int c = t & 127;
    float m = 0.f;
    for (int k = 0; k < 128; ++k) m = fmaxf(m, fabsf(W[k * CH + c]));
    float inv = (m > 0.f) ? 127.0f / m : 0.f;
    for (int k = 0; k < 128; ++k) {
        int q = __float2int_rn(W[k * CH + c] * inv);
        WT[c * CH + k] = (unsigned char)(q & 255);
    }
    wcs[c] = m * (1.0f / 127.0f);
    if (t < 128) {
        float a = gamma[c] * rsqrtf(rvar[c] + BN_EPS);
        A1[c] = a;
        B1[c] = (b1[c] - rmean[c]) * a + beta[c];
    }
}

// ---------------- bucket histogram ----------------
__global__ __launch_bounds__(256) void k_bhist(const int* __restrict__ dst, int* __restrict__ bcnt) {
    __shared__ int lh[NBUCK];
    for (int i = threadIdx.x; i < NBUCK; i += 256) lh[i] = 0;
    __syncthreads();
    for (int e = blockIdx.x * 256 + threadIdx.x; e < N_EDGES; e += gridDim.x * 256)
        atomicAdd(&lh[dst[e] >> 7], 1);
    __syncthreads();
    for (int i = threadIdx.x; i < NBUCK; i += 256) {
        int v = lh[i];
        if (v) atomicAdd(&bcnt[i], v);
    }
}

// ---------------- scan 1024 -> exclusive bases + cursor copy ----------------
__global__ __launch_bounds__(256) void k_bscan(const int* __restrict__ in, int* __restrict__ out,
                                               int* __restrict__ cur) {
    __shared__ int sm[256];
    int t = threadIdx.x;
    int4 v = *(const int4*)&in[t * 4];
    int tsum = v.x + v.y + v.z + v.w;
    sm[t] = tsum;
    __syncthreads();
    for (int off = 1; off < 256; off <<= 1) {
        int val = sm[t];
        int add = (t >= off) ? sm[t - off] : 0;
        __syncthreads();
        sm[t] = val + add;
        __syncthreads();
    }
    int excl = sm[t] - tsum;
    int o0 = excl, o1 = excl + v.x, o2 = o1 + v.y, o3 = o2 + v.z;
    out[t * 4] = o0; out[t * 4 + 1] = o1; out[t * 4 + 2] = o2; out[t * 4 + 3] = o3;
    if (cur) { cur[t * 4] = o0; cur[t * 4 + 1] = o1; cur[t * 4 + 2] = o2; cur[t * 4 + 3] = o3; }
}

// ---------------- bin edges into per-bucket packed segments ----------------
__global__ __launch_bounds__(256) void k_bin(const int* __restrict__ src, const int* __restrict__ dst,
                                             int* __restrict__ bcur, unsigned int* __restrict__ pairs) {
    __shared__ int lhist[NBUCK];
    __shared__ int lbase[NBUCK];
    int t = threadIdx.x;
    for (int i = t; i < NBUCK; i += 256) lhist[i] = 0;
    __syncthreads();
    int base = blockIdx.x * EPB;
    int lim = min(base + EPB, N_EDGES);
    for (int e = base + t; e < lim; e += 256)
        atomicAdd(&lhist[dst[e] >> 7], 1);
    __syncthreads();
    for (int i = t; i < NBUCK; i += 256) {
        int h = lhist[i];
        lbase[i] = h ? atomicAdd(&bcur[i], h) : 0;
        lhist[i] = 0;
    }
    __syncthreads();
    for (int e = base + t; e < lim; e += 256) {
        int d = dst[e];
        int b = d >> 7;
        int r = atomicAdd(&lhist[b], 1);
        pairs[lbase[b] + r] = ((unsigned int)src[e] << 7) | ((unsigned int)d & 127u);
    }
}

// ---------------- per-bucket src-class sort + dinv ----------------
// Sort each bucket's edge segment by src class (src>>10, 98 classes). All SpMM
// blocks then sweep src space in the same order -> live xq window ~2MB, L2-hot.
__global__ __launch_bounds__(256) void k_bsort(const unsigned int* __restrict__ pairs,
                                               const int* __restrict__ boffs,
                                               float* __restrict__ dinv,
                                               unsigned int* __restrict__ pairs2) {
    __shared__ int ccnt[128];
    __shared__ int cbase[128];
    __shared__ int ncnt[128];
    __shared__ int lsc[128];
    int b = blockIdx.x, t = threadIdx.x;
    if (t < 128) { ccnt[t] = 0; ncnt[t] = 0; }
    __syncthreads();
    int p0 = boffs[b];
    int p1 = (b == NBUCK - 1) ? N_EDGES : boffs[b + 1];
    for (int p = p0 + t; p < p1; p += 256) {
        unsigned int e = pairs[p];
        atomicAdd(&ccnt[(int)(e >> 7) >> 10], 1);
        atomicAdd(&ncnt[e & 127u], 1);
    }
    __syncthreads();
    if (t < 128) lsc[t] = ccnt[t];
    __syncthreads();
    for (int off = 1; off < 128; off <<= 1) {
        int val = 0, add = 0;
        if (t < 128) { val = lsc[t]; add = (t >= off) ? lsc[t - off] : 0; }
        __syncthreads();
        if (t < 128) lsc[t] = val + add;
        __syncthreads();
    }
    if (t < 128) {
        cbase[t] = p0 + lsc[t] - ccnt[t];
        ccnt[t] = 0;
        int node = (b << 7) + t;
        if (node < N_NODES) dinv[node] = rsqrtf((float)(ncnt[t] + 1));
    }
    __syncthreads();
    for (int p = p0 + t; p < p1; p += 256) {
        unsigned int e = pairs[p];
        int cl = (int)(e >> 7) >> 10;
        int r = atomicAdd(&ccnt[cl], 1);
        pairs2[cbase[cl] + r] = e;
    }
}

// ---------------- MFMA int8 GEMM: Y_int8[N,128] = quant(Xq*xs @ WqT*wcs), + spre ----------------
__global__ __launch_bounds__(256) void k_gemm_mfma(
    const unsigned char* __restrict__ Xq, const float* __restrict__ xs,
    const unsigned char* __restrict__ WT, const float* __restrict__ wcs,
    const float* __restrict__ dinvp, unsigned char* __restrict__ Yq, float* __restrict__ ospre) {
    __shared__ float ep[4][16][132];
    int t = threadIdx.x;
    int w = t >> 6;
    int lane = t & 63;
    int quad = lane >> 4, l16 = lane & 15;
    int row0 = blockIdx.x * 64 + w * 16;

    int arow = row0 + l16;
    if (arow >= N_NODES) arow = N_NODES - 1;
    i32x4 a0 = *(const i32x4*)&Xq[(size_t)arow * CH + quad * 16];
    i32x4 a1 = *(const i32x4*)&Xq[(size_t)arow * CH + 64 + quad * 16];

    i32x4 acc[8];
    #pragma unroll
    for (int i = 0; i < 8; ++i) acc[i] = (i32x4){0, 0, 0, 0};

    #pragma unroll
    for (int tt = 0; tt < 8; ++tt) {
        int n = tt * 16 + l16;
        i32x4 b0 = *(const i32x4*)&WT[(size_t)n * CH + quad * 16];
        i32x4 b1 = *(const i32x4*)&WT[(size_t)n * CH + 64 + quad * 16];
        acc[tt] = __builtin_amdgcn_mfma_i32_16x16x64_i8(a0, b0, acc[tt], 0, 0, 0);
        acc[tt] = __builtin_amdgcn_mfma_i32_16x16x64_i8(a1, b1, acc[tt], 0, 0, 0);
    }

    float xsr[4];
    #pragma unroll
    for (int r = 0; r < 4; ++r) {
        int rr = row0 + quad * 4 + r;
        xsr[r] = xs[(rr < N_NODES) ? rr : (N_NODES - 1)];
    }
    #pragma unroll
    for (int tt = 0; tt < 8; ++tt) {
        float wc = wcs[tt * 16 + l16];
        #pragma unroll
        for (int r = 0; r < 4; ++r)
            ep[w][quad * 4 + r][tt * 16 + l16] = (float)acc[tt][r] * xsr[r] * wc;
    }
    __syncthreads();

    int rl = lane >> 2, part = lane & 3;
    int grow = row0 + rl;
    float v[32];
    float m = 0.f;
    #pragma unroll
    for (int i = 0; i < 32; ++i) {
        v[i] = ep[w][rl][part * 32 + i];
        m = fmaxf(m, fabsf(v[i]));
    }
    m = fmaxf(m, __shfl_xor(m, 1, 64));
    m = fmaxf(m, __shfl_xor(m, 2, 64));
    if (grow < N_NODES) {
        float inv = (m > 0.f) ? 127.0f / m : 0.f;
        unsigned int o[8];
        #pragma unroll
        for (int q = 0; q < 8; ++q) o[q] = packq(&v[q * 4], inv);
        uint4* dst0 = (uint4*)&Yq[(size_t)grow * CH + part * 32];
        dst0[0] = make_uint4(o[0], o[1], o[2], o[3]);
        dst0[1] = make_uint4(o[4], o[5], o[6], o[7]);
        if (part == 0) ospre[grow] = (m * (1.0f / 127.0f)) * dinvp[grow];
    }
}

// ---------------- SpMM v5: src-swept, dst-bucket accumulator in LDS ----------------
// Block = 1 dst bucket. accf[128 rows][128 ch] f32 (64KB LDS), bank-swizzled
// ch' = (ch + 5*dl) & 127. Edges (class-sorted) processed 8 threads/edge x 16B.
// dinv[dst] applied in epilogue; spre[src] carries scale*dinv[src].
#define ACC16LDS(dlv, partv, fv, qv)                                                   \
    { int _C = ((dlv) * 5) & 127; int _bi = (dlv) << 7; int _c0 = (partv) * 16;        \
      unsigned int _wd[4] = {qv.x, qv.y, qv.z, qv.w};                                  \
      _Pragma("unroll") for (int _u = 0; _u < 4; ++_u) {                               \
        int _a = (int)_wd[_u];                                                         \
        atomicAdd(&accf[_bi + ((_c0 + _u * 4 + 0 + _C) & 127)], fv * (float)((_a << 24) >> 24)); \
        atomicAdd(&accf[_bi + ((_c0 + _u * 4 + 1 + _C) & 127)], fv * (float)((_a << 16) >> 24)); \
        atomicAdd(&accf[_bi + ((_c0 + _u * 4 + 2 + _C) & 127)], fv * (float)((_a << 8) >> 24));  \
        atomicAdd(&accf[_bi + ((_c0 + _u * 4 + 3 + _C) & 127)], fv * (float)(_a >> 24));          \
      } }

#define SWEEP_ACC()                                                                    \
    __shared__ float accf[16384];                                                      \
    int b = blockIdx.x, tid = threadIdx.x;                                             \
    for (int i = tid; i < 16384; i += 256) accf[i] = 0.f;                              \
    __syncthreads();                                                                   \
    {                                                                                  \
        int p0 = boffs[b];                                                             \
        int p1 = (b == NBUCK - 1) ? N_EDGES : boffs[b + 1];                            \
        int nE = p1 - p0;                                                              \
        int eslot = tid >> 3, part = tid & 7;                                          \
        for (int base = 0; base < nE; base += 64) {                                    \
            int k0 = base + eslot, k1 = base + 32 + eslot;                             \
            unsigned int e0 = pairs2[p0 + ((k0 < nE) ? k0 : 0)];                       \
            unsigned int e1 = pairs2[p0 + ((k1 < nE) ? k1 : 0)];                       \
            int s0 = (int)(e0 >> 7), dl0 = (int)(e0 & 127u);                           \
            int s1 = (int)(e1 >> 7), dl1 = (int)(e1 & 127u);                           \
            float f0 = (k0 < nE) ? spre[s0] : 0.f;                                     \
            float f1 = (k1 < nE) ? spre[s1] : 0.f;                                     \
            u32x4 q0 = xqv[(size_t)s0 * 8 + part];                                     \
            u32x4 q1 = xqv[(size_t)s1 * 8 + part];                                     \
            ACC16LDS(dl0, part, f0, q0)                                                \
            ACC16LDS(dl1, part, f1, q1)                                                \
        }                                                                              \
    }                                                                                  \
    __syncthreads();

// ---------------- SpMM layer 1: sweep + self + dinv + BN/ReLU -> int8 + raw scale ----------------
__global__ __launch_bounds__(256, 2) void k_spmm_bn_relu(
    const u32x4* __restrict__ xqv, const unsigned int* __restrict__ pairs2,
    const int* __restrict__ boffs, const float* __restrict__ dinv,
    const float* __restrict__ spre, const float* __restrict__ A1, const float* __restrict__ B1,
    unsigned char* __restrict__ outq, float* __restrict__ osraw) {
    SWEEP_ACC()
    int dl = tid >> 1, hf = tid & 1;
    int node = (b << 7) + dl;
    if (node < N_NODES) {
        float di = dinv[node];
        float fs = spre[node];
        int C = (dl * 5) & 127;
        int rowb = dl << 7;
        unsigned int sw[16];
        const u32x4* xr = &xqv[(size_t)node * 8 + hf * 4];
        #pragma unroll
        for (int i = 0; i < 4; ++i) {
            u32x4 q = xr[i];
            sw[i * 4 + 0] = q.x; sw[i * 4 + 1] = q.y; sw[i * 4 + 2] = q.z; sw[i * 4 + 3] = q.w;
        }
        float r[64];
        float m = 0.f;
        #pragma unroll
        for (int j = 0; j < 64; ++j) {
            int ch = hf * 64 + j;
            int a8 = ((int)(sw[j >> 2] << ((3 - (j & 3)) * 8))) >> 24;
            float a = accf[rowb + ((ch + C) & 127)] + fs * (float)a8;
            a *= di;
            a = fmaxf(a * A1[ch] + B1[ch], 0.f);
            r[j] = a;
            m = fmaxf(m, a);
        }
        m = fmaxf(m, __shfl_xor(m, 1, 64));
        float inv = (m > 0.f) ? 127.0f / m : 0.f;
        unsigned int o[16];
        #pragma unroll
        for (int j = 0; j < 16; ++j) o[j] = packq(&r[j * 4], inv);
        u32x4* outp = (u32x4*)&outq[(size_t)node * CH + hf * 64];
        #pragma unroll
        for (int i = 0; i < 4; ++i)
            outp[i] = (u32x4){o[i * 4], o[i * 4 + 1], o[i * 4 + 2], o[i * 4 + 3]};
        if (hf == 0) osraw[node] = m * (1.0f / 127.0f);
    }
}

// ---------------- SpMM layer 2: sweep + self + dinv + bias + per-graph pool ----------------
__global__ __launch_bounds__(256, 2) void k_spmm_pool(
    const u32x4* __restrict__ xqv, const unsigned int* __restrict__ pairs2,
    const int* __restrict__ boffs, const float* __restrict__ dinv,
    const float* __restrict__ spre, const float* __restrict__ bias,
    const int* __restrict__ batch, float* __restrict__ psum, int* __restrict__ pcnt) {
    SWEEP_ACC()
    int dl = tid >> 1, hf = tid & 1;
    int node = (b << 7) + dl;
    float r[64];
    if (node < N_NODES) {
        float di = dinv[node];
        float fs = spre[node];
        int C = (dl * 5) & 127;
        int rowb = dl << 7;
        unsigned int sw[16];
        const u32x4* xr = &xqv[(size_t)node * 8 + hf * 4];
        #pragma unroll
        for (int i = 0; i < 4; ++i) {
            u32x4 q = xr[i];
            sw[i * 4 + 0] = q.x; sw[i * 4 + 1] = q.y; sw[i * 4 + 2] = q.z; sw[i * 4 + 3] = q.w;
        }
        #pragma unroll
        for (int j = 0; j < 64; ++j) {
            int ch = hf * 64 + j;
            int a8 = ((int)(sw[j >> 2] << ((3 - (j & 3)) * 8))) >> 24;
            float a = accf[rowb + ((ch + C) & 127)] + fs * (float)a8;
            r[j] = a * di + bias[ch];
        }
    }
    __syncthreads();
    if (node < N_NODES) {
        #pragma unroll
        for (int j = 0; j < 64; ++j)
            accf[(dl << 7) + hf * 64 + j] = r[j];
    }
    __syncthreads();
    // per-graph segmented reduction (batch sorted -> few runs per bucket)
    int ch = tid & 127, seg = tid >> 7;
    {
        int gprev = -1;
        float s = 0.f;
        for (int rr = seg * 64; rr < seg * 64 + 64; ++rr) {
            int nd = (b << 7) + rr;
            if (nd >= N_NODES) break;
            int g = batch[nd];
            if (g != gprev) {
                if (gprev >= 0) unsafeAtomicAdd(&psum[gprev * CH + ch], s);
                s = 0.f;
                gprev = g;
            }
            s += accf[(rr << 7) + ch];
        }
        if (gprev >= 0) unsafeAtomicAdd(&psum[gprev * CH + ch], s);
        if (ch == 0) {
            int gp = -1, cnt = 0;
            for (int rr = seg * 64; rr < seg * 64 + 64; ++rr) {
                int nd = (b << 7) + rr;
                if (nd >= N_NODES) break;
                int g = batch[nd];
                if (g != gp) { if (gp >= 0) atomicAdd(&pcnt[gp], cnt); cnt = 0; gp = g; }
                cnt++;
            }
            if (gp >= 0) atomicAdd(&pcnt[gp], cnt);
        }
    }
}

// ---------------- head ----------------
__global__ __launch_bounds__(128) void k_head(const float* __restrict__ psum, const int* __restrict__ pcnt,
                                              const float* __restrict__ fw1, const float* __restrict__ fb1,
                                              const float* __restrict__ cw, const float* __restrict__ cb,
                                              float* __restrict__ out) {
    __shared__ float fws[128 * 64];
    for (int i = threadIdx.x; i < 128 * 64; i += 128) fws[i] = fw1[i];
    __syncthreads();
    int g = threadIdx.x;
    float z[64];
    #pragma unroll
    for (int j = 0; j < 64; ++j) z[j] = fb1[j];
    float cnt = fmaxf((float)pcnt[g], 1.f);
    float inv = 1.f / cnt;
    for (int c = 0; c < 128; ++c) {
        float p = psum[g * CH + c] * inv;
        #pragma unroll
        for (int j = 0; j < 64; ++j) z[j] += p * fws[c * 64 + j];
    }
    float o0 = cb[0], o1 = cb[1];
    #pragma unroll
    for (int j = 0; j < 64; ++j) {
        float zz = fmaxf(z[j], 0.f);
        o0 += zz * cw[j * 2];
        o1 += zz * cw[j * 2 + 1];
    }
    out[g * 2] = o0;
    out[g * 2 + 1] = o1;
}

extern "C" void kernel_launch(void* const* d_in, const int* in_sizes, int n_in,
                              void* d_out, int out_size, void* d_ws, size_t ws_size,
                              hipStream_t stream) {
    const float* x     = (const float*)d_in[0];
    const int*   ei    = (const int*)d_in[1];
    const int*   batch = (const int*)d_in[2];
    const float* W1    = (const float*)d_in[3];
    const float* b1    = (const float*)d_in[4];
    const float* gamma = (const float*)d_in[5];
    const float* beta  = (const float*)d_in[6];
    const float* rmean = (const float*)d_in[7];
    const float* rvar  = (const float*)d_in[8];
    const float* W2    = (const float*)d_in[9];
    const float* b2    = (const float*)d_in[10];
    const float* fw1   = (const float*)d_in[11];
    const float* fb1   = (const float*)d_in[12];
    const float* cw    = (const float*)d_in[13];
    const float* cb    = (const float*)d_in[14];
    const int* srcp = ei;
    const int* dstp = ei + N_EDGES;

    char* w = (char*)d_ws;
    // zeroed region first
    int*   bcnt  = (int*)w;   w += 4096;
    float* psum  = (float*)w; w += 65536;
    int*   pcnt  = (int*)w;   w += 512;
    size_t zbytes = 4096 + 65536 + 512;
    // non-zeroed
    int*   deg   = (int*)w;   w += 400000;   // (unused in v5, layout kept)
    int*   offs  = (int*)w;   w += 400000;   // (unused in v5, layout kept)
    float* dinv  = (float*)w; w += 400000;
    float* xsA   = (float*)w; w += 400000;
    float* spreA = (float*)w; w += 400000;
    float* srawB = (float*)w; w += 400000;
    float* spreC = (float*)w; w += 400000;
    float* A1    = (float*)w; w += 512;
    float* B1    = (float*)w; w += 512;
    float* wcs1  = (float*)w; w += 512;
    float* wcs2  = (float*)w; w += 512;
    unsigned char* Wq1T = (unsigned char*)w; w += 16384;
    unsigned char* Wq2T = (unsigned char*)w; w += 16384;
    int*   boffs = (int*)w;   w += 4096;
    int*   bcur  = (int*)w;   w += 4096;
    unsigned int* pairs  = (unsigned int*)w; w += 12800000;
    unsigned int* pairs2 = (unsigned int*)w; w += 12800000;  // class-sorted edges
    unsigned char* Xq   = (unsigned char*)w; w += 12800000;  // int8 [100k,128]
    unsigned char* bufA = (unsigned char*)w; w += 12800000;
    unsigned char* bufB = (unsigned char*)w; w += 12800000;
    unsigned char* bufC = (unsigned char*)w; w += 12800000;
    (void)deg; (void)offs;

    hipMemsetAsync(d_ws, 0, zbytes, stream);
    k_quantx<<<6250, 256, 0, stream>>>(x, Xq, xsA);
    k_bhist<<<200, 256, 0, stream>>>(dstp, bcnt);
    k_bscan<<<1, 256, 0, stream>>>(bcnt, boffs, bcur);
    k_bin<<<(N_EDGES + EPB - 1) / EPB, 256, 0, stream>>>(srcp, dstp, bcur, pairs);
    k_bsort<<<NBUCK, 256, 0, stream>>>(pairs, boffs, dinv, pairs2);
    k_prepW<<<1, 256, 0, stream>>>(W1, W2, gamma, beta, rmean, rvar, b1,
                                   Wq1T, wcs1, Wq2T, wcs2, A1, B1);
    k_gemm_mfma<<<1563, 256, 0, stream>>>(Xq, xsA, Wq1T, wcs1, dinv, bufA, spreA);
    k_spmm_bn_relu<<<NBUCK, 256, 0, stream>>>((const u32x4*)bufA, pairs2, boffs, dinv, spreA,
                                              A1, B1, bufB, srawB);
    k_gemm_mfma<<<1563, 256, 0, stream>>>(bufB, srawB, Wq2T, wcs2, dinv, bufC, spreC);
    k_spmm_pool<<<NBUCK, 256, 0, stream>>>((const u32x4*)bufC, pairs2, boffs, dinv, spreC,
                                           b2, batch, psum, pcnt);
    k_head<<<1, 128, 0, stream>>>(psum, pcnt, fw1, fb1, cw, cb, (float*)d_out);
}

// Round 7
// 555.326 us; speedup vs baseline: 10.3082x; 10.3082x over previous
//
#include <hip/hip_runtime.h>
#include <hip/hip_bf16.h>

#define N_NODES 100000
#define N_EDGES 3200000
#define CH 128
#define NG 128
#define BN_EPS 1e-5f
#define NBUCK 1024   // bucket = dst >> 7 (128 nodes per bucket)
#define EPB 16384    // edges per k_bin block
#define NSPB 1563    // spmm blocks: 64 rows each, co-resident grid

using i32x4 = __attribute__((ext_vector_type(4))) int;

__device__ __forceinline__ unsigned int packq(const float* v, float inv) {
    int q0 = __float2int_rn(v[0] * inv), q1 = __float2int_rn(v[1] * inv);
    int q2 = __float2int_rn(v[2] * inv), q3 = __float2int_rn(v[3] * inv);
    return (unsigned int)(q0 & 255) | ((unsigned int)(q1 & 255) << 8) |
           ((unsigned int)(q2 & 255) << 16) | ((unsigned int)(q3 & 255) << 24);
}

// ---------------- quantize x rows to int8 + per-row scale ----------------
__global__ __launch_bounds__(256) void k_quantx(const float* __restrict__ x,
                                                unsigned char* __restrict__ Xq,
                                                float* __restrict__ xs) {
    int t = threadIdx.x;
    int row = blockIdx.x * 16 + (t >> 4);
    int seg = t & 15;
    const float4* p = (const float4*)&x[(size_t)row * CH + seg * 8];
    float4 a = p[0], b = p[1];
    float v[8] = {a.x, a.y, a.z, a.w, b.x, b.y, b.z, b.w};
    float m = 0.f;
    #pragma unroll
    for (int i = 0; i < 8; ++i) m = fmaxf(m, fabsf(v[i]));
    m = fmaxf(m, __shfl_xor(m, 1, 64));
    m = fmaxf(m, __shfl_xor(m, 2, 64));
    m = fmaxf(m, __shfl_xor(m, 4, 64));
    m = fmaxf(m, __shfl_xor(m, 8, 64));
    float inv = (m > 0.f) ? 127.0f / m : 0.f;
    uint2 pk;
    pk.x = packq(&v[0], inv);
    pk.y = packq(&v[4], inv);
    *(uint2*)&Xq[(size_t)row * CH + seg * 8] = pk;
    if (seg == 0) xs[row] = m * (1.0f / 127.0f);
}

// ---------------- quantize W1/W2 per column (transposed) + BN fold ----------------
__global__ __launch_bounds__(256) void k_prepW(
    const float* __restrict__ W1, const float* __restrict__ W2,
    const float* __restrict__ gamma, const float* __restrict__ beta,
    const float* __restrict__ rmean, const float* __restrict__ rvar, const float* __restrict__ b1,
    unsigned char* __restrict__ Wq1T, float* __restrict__ wcs1,
    unsigned char* __restrict__ Wq2T, float* __restrict__ wcs2,
    float* __restrict__ A1, float* __restrict__ B1) {
    int t = threadIdx.x;
    const float* W = (t < 128) ? W1 : W2;
    unsigned char* WT = (t < 128) ? Wq1T : Wq2T;
    float* wcs = (t < 128) ? wcs1 : wcs2;
    int c = t & 127;
    float m = 0.f;
    for (int k = 0; k < 128; ++k) m = fmaxf(m, fabsf(W[k * CH + c]));
    float inv = (m > 0.f) ? 127.0f / m : 0.f;
    for (int k = 0; k < 128; ++k) {
        int q = __float2int_rn(W[k * CH + c] * inv);
        WT[c * CH + k] = (unsigned char)(q & 255);
    }
    wcs[c] = m * (1.0f / 127.0f);
    if (t < 128) {
        float a = gamma[c] * rsqrtf(rvar[c] + BN_EPS);
        A1[c] = a;
        B1[c] = (b1[c] - rmean[c]) * a + beta[c];
    }
}

// ---------------- bucket histogram ----------------
__global__ __launch_bounds__(256) void k_bhist(const int* __restrict__ dst, int* __restrict__ bcnt) {
    __shared__ int lh[NBUCK];
    for (int i = threadIdx.x; i < NBUCK; i += 256) lh[i] = 0;
    __syncthreads();
    for (int e = blockIdx.x * 256 + threadIdx.x; e < N_EDGES; e += gridDim.x * 256)
        atomicAdd(&lh[dst[e] >> 7], 1);
    __syncthreads();
    for (int i = threadIdx.x; i < NBUCK; i += 256) {
        int v = lh[i];
        if (v) atomicAdd(&bcnt[i], v);
    }
}

// ---------------- scan 1024 -> exclusive bases + cursor copy ----------------
__global__ __launch_bounds__(256) void k_bscan(const int* __restrict__ in, int* __restrict__ out,
                                               int* __restrict__ cur) {
    __shared__ int sm[256];
    int t = threadIdx.x;
    int4 v = *(const int4*)&in[t * 4];
    int tsum = v.x + v.y + v.z + v.w;
    sm[t] = tsum;
    __syncthreads();
    for (int off = 1; off < 256; off <<= 1) {
        int val = sm[t];
        int add = (t >= off) ? sm[t - off] : 0;
        __syncthreads();
        sm[t] = val + add;
        __syncthreads();
    }
    int excl = sm[t] - tsum;
    int o0 = excl, o1 = excl + v.x, o2 = o1 + v.y, o3 = o2 + v.z;
    out[t * 4] = o0; out[t * 4 + 1] = o1; out[t * 4 + 2] = o2; out[t * 4 + 3] = o3;
    if (cur) { cur[t * 4] = o0; cur[t * 4 + 1] = o1; cur[t * 4 + 2] = o2; cur[t * 4 + 3] = o3; }
}

// ---------------- bin edges into per-bucket packed segments ----------------
__global__ __launch_bounds__(256) void k_bin(const int* __restrict__ src, const int* __restrict__ dst,
                                             int* __restrict__ bcur, unsigned int* __restrict__ pairs) {
    __shared__ int lhist[NBUCK];
    __shared__ int lbase[NBUCK];
    int t = threadIdx.x;
    for (int i = t; i < NBUCK; i += 256) lhist[i] = 0;
    __syncthreads();
    int base = blockIdx.x * EPB;
    int lim = min(base + EPB, N_EDGES);
    for (int e = base + t; e < lim; e += 256)
        atomicAdd(&lhist[dst[e] >> 7], 1);
    __syncthreads();
    for (int i = t; i < NBUCK; i += 256) {
        int h = lhist[i];
        lbase[i] = h ? atomicAdd(&bcur[i], h) : 0;
        lhist[i] = 0;
    }
    __syncthreads();
    for (int e = base + t; e < lim; e += 256) {
        int d = dst[e];
        int b = d >> 7;
        int r = atomicAdd(&lhist[b], 1);
        pairs[lbase[b] + r] = ((unsigned int)src[e] << 7) | ((unsigned int)d & 127u);
    }
}

// ---------------- per-bucket CSR fill + deg/offs/dinv, src-octant ordered ----------------
// Per-node counters widened to (node, src>>14): each row's perm segment comes out
// grouped by ascending src class (8 classes x 1.6MB of xq each). The serialized
// SpMM walk (chunk=8) + co-resident grid then sweeps src space in lockstep.
__global__ __launch_bounds__(256) void k_bfill(const unsigned int* __restrict__ pairs,
                                               const int* __restrict__ boffs,
                                               int* __restrict__ offs, int* __restrict__ deg,
                                               float* __restrict__ dinv, int* __restrict__ perm) {
    __shared__ int lcur[1024];
    __shared__ int loff[1024];
    __shared__ int sm[256];
    int b = blockIdx.x;
    int t = threadIdx.x;
    for (int i = t; i < 1024; i += 256) lcur[i] = 0;
    __syncthreads();
    int p0 = boffs[b];
    int p1 = (b == NBUCK - 1) ? N_EDGES : boffs[b + 1];
    for (int p = p0 + t; p < p1; p += 256) {
        unsigned int e = pairs[p];
        int idx = (int)((e & 127u) << 3) | (int)((e >> 7) >> 14);
        atomicAdd(&lcur[idx], 1);
    }
    __syncthreads();
    int4 v = *(const int4*)&lcur[t * 4];
    int tsum = v.x + v.y + v.z + v.w;
    sm[t] = tsum;
    __syncthreads();
    for (int off = 1; off < 256; off <<= 1) {
        int val = sm[t];
        int add = (t >= off) ? sm[t - off] : 0;
        __syncthreads();
        sm[t] = val + add;
        __syncthreads();
    }
    int excl = sm[t] - tsum + p0;
    loff[t * 4]     = excl;
    loff[t * 4 + 1] = excl + v.x;
    loff[t * 4 + 2] = excl + v.x + v.y;
    loff[t * 4 + 3] = excl + v.x + v.y + v.z;
    lcur[t * 4] = 0; lcur[t * 4 + 1] = 0; lcur[t * 4 + 2] = 0; lcur[t * 4 + 3] = 0;
    __syncthreads();
    if (t < 128) {
        int node = (b << 7) + t;
        if (node < N_NODES) {
            int o0 = loff[t * 8];
            int o1 = (t == 127) ? p1 : loff[(t + 1) * 8];
            int cnt = o1 - o0;
            offs[node] = o0;
            deg[node] = cnt;
            dinv[node] = rsqrtf((float)(cnt + 1));
        }
    }
    __syncthreads();
    for (int p = p0 + t; p < p1; p += 256) {
        unsigned int e = pairs[p];
        int src = (int)(e >> 7);
        int idx = (int)((e & 127u) << 3) | (src >> 14);
        int r = atomicAdd(&lcur[idx], 1);
        perm[loff[idx] + r] = src;
    }
}

// ---------------- MFMA int8 GEMM: Y_int8[N,128] = quant(Xq*xs @ WqT*wcs), + spre ----------------
__global__ __launch_bounds__(256) void k_gemm_mfma(
    const unsigned char* __restrict__ Xq, const float* __restrict__ xs,
    const unsigned char* __restrict__ WT, const float* __restrict__ wcs,
    const float* __restrict__ dinvp, unsigned char* __restrict__ Yq, float* __restrict__ ospre) {
    __shared__ float ep[4][16][132];
    int t = threadIdx.x;
    int w = t >> 6;
    int lane = t & 63;
    int quad = lane >> 4, l16 = lane & 15;
    int row0 = blockIdx.x * 64 + w * 16;

    int arow = row0 + l16;
    if (arow >= N_NODES) arow = N_NODES - 1;
    i32x4 a0 = *(const i32x4*)&Xq[(size_t)arow * CH + quad * 16];
    i32x4 a1 = *(const i32x4*)&Xq[(size_t)arow * CH + 64 + quad * 16];

    i32x4 acc[8];
    #pragma unroll
    for (int i = 0; i < 8; ++i) acc[i] = (i32x4){0, 0, 0, 0};

    #pragma unroll
    for (int tt = 0; tt < 8; ++tt) {
        int n = tt * 16 + l16;
        i32x4 b0 = *(const i32x4*)&WT[(size_t)n * CH + quad * 16];
        i32x4 b1 = *(const i32x4*)&WT[(size_t)n * CH + 64 + quad * 16];
        acc[tt] = __builtin_amdgcn_mfma_i32_16x16x64_i8(a0, b0, acc[tt], 0, 0, 0);
        acc[tt] = __builtin_amdgcn_mfma_i32_16x16x64_i8(a1, b1, acc[tt], 0, 0, 0);
    }

    float xsr[4];
    #pragma unroll
    for (int r = 0; r < 4; ++r) {
        int rr = row0 + quad * 4 + r;
        xsr[r] = xs[(rr < N_NODES) ? rr : (N_NODES - 1)];
    }
    #pragma unroll
    for (int tt = 0; tt < 8; ++tt) {
        float wc = wcs[tt * 16 + l16];
        #pragma unroll
        for (int r = 0; r < 4; ++r)
            ep[w][quad * 4 + r][tt * 16 + l16] = (float)acc[tt][r] * xsr[r] * wc;
    }
    __syncthreads();

    int rl = lane >> 2, part = lane & 3;
    int grow = row0 + rl;
    float v[32];
    float m = 0.f;
    #pragma unroll
    for (int i = 0; i < 32; ++i) {
        v[i] = ep[w][rl][part * 32 + i];
        m = fmaxf(m, fabsf(v[i]));
    }
    m = fmaxf(m, __shfl_xor(m, 1, 64));
    m = fmaxf(m, __shfl_xor(m, 2, 64));
    if (grow < N_NODES) {
        float inv = (m > 0.f) ? 127.0f / m : 0.f;
        unsigned int o[8];
        #pragma unroll
        for (int q = 0; q < 8; ++q) o[q] = packq(&v[q * 4], inv);
        uint4* dst0 = (uint4*)&Yq[(size_t)grow * CH + part * 32];
        dst0[0] = make_uint4(o[0], o[1], o[2], o[3]);
        dst0[1] = make_uint4(o[4], o[5], o[6], o[7]);
        if (part == 0) ospre[grow] = (m * (1.0f / 127.0f)) * dinvp[grow];
    }
}

// ---------------- SpMM v7: persistent co-resident grid, serialized class walk ----------------
// 1563 blocks x 256 thr, all co-resident (7 blk/CU max, 28 waves/CU). Block owns 64
// rows (16 row-groups of 4). Edges per row are class-sorted (k_bfill); the chunk-8
// serial walk makes every wave sweep src classes in ascending order simultaneously,
// so the live xq window (~2-3MB) stays L2-resident on every XCD.
#define ACCI8(f, v)                                                                    \
    { int _a = (int)v.x, _b = (int)v.y;                                                \
      acc[0] += f * (float)((_a << 24) >> 24);                                         \
      acc[1] += f * (float)((_a << 16) >> 24);                                         \
      acc[2] += f * (float)((_a << 8) >> 24);                                          \
      acc[3] += f * (float)(_a >> 24);                                                 \
      acc[4] += f * (float)((_b << 24) >> 24);                                         \
      acc[5] += f * (float)((_b << 16) >> 24);                                         \
      acc[6] += f * (float)((_b << 8) >> 24);                                          \
      acc[7] += f * (float)(_b >> 24); }

#define SPMM_ROW_GATHER()                                                              \
    float di = 0.f; int beg = 0, end = 0;                                              \
    if (valid) { di = dinv[row]; beg = offs[row]; end = beg + deg[row]; }              \
    float acc[8];                                                                      \
    _Pragma("unroll") for (int j = 0; j < 8; ++j) acc[j] = 0.f;                        \
    for (int cb = beg; cb < end; cb += 8) {                                            \
        int k0 = cb + g, k1 = cb + g + 4;                                              \
        int ka0 = (k0 < end) ? k0 : (end - 1);                                         \
        int ka1 = (k1 < end) ? k1 : (end - 1);                                         \
        int s0 = perm[ka0], s1 = perm[ka1];                                            \
        float f0 = (k0 < end) ? di : 0.f;                                              \
        float f1 = (k1 < end) ? di : 0.f;                                              \
        f0 *= spre[s0]; f1 *= spre[s1];                                                \
        uint2 v0 = xq[(size_t)s0 * 16 + c];                                            \
        uint2 v1 = xq[(size_t)s1 * 16 + c];                                            \
        ACCI8(f0, v0) ACCI8(f1, v1)                                                    \
    }                                                                                  \
    _Pragma("unroll") for (int j = 0; j < 8; ++j) {                                    \
        acc[j] += __shfl_xor(acc[j], 16, 64);                                          \
        acc[j] += __shfl_xor(acc[j], 32, 64);                                          \
    }

// ---------------- SpMM layer 1: aggregate + folded BN/ReLU -> int8 + raw scale ----------------
__global__ __launch_bounds__(256) void k_spmm_bn_relu(
    const uint2* __restrict__ xq, const int* __restrict__ perm, const int* __restrict__ offs,
    const int* __restrict__ deg, const float* __restrict__ dinv, const float* __restrict__ spre,
    const float* __restrict__ A1, const float* __restrict__ B1,
    uint2* __restrict__ outq, float* __restrict__ osraw) {
    int w = threadIdx.x >> 6;
    int lane = threadIdx.x & 63;
    int g = lane >> 4, c = lane & 15;
    int base = blockIdx.x * 64;
    for (int i = 0; i < 16; ++i) {
        int row = __builtin_amdgcn_readfirstlane(base + i * 4 + w);
        bool valid = row < N_NODES;
        SPMM_ROW_GATHER()
        if (g == 0 && valid) {
            uint2 v = xq[(size_t)row * 16 + c];
            float fs = di * spre[row];
            ACCI8(fs, v)
            int ch = c * 8;
            float r[8];
            const float4* A4 = (const float4*)&A1[ch];
            const float4* B4 = (const float4*)&B1[ch];
            #pragma unroll
            for (int q = 0; q < 2; ++q) {
                float4 aa = A4[q], bb = B4[q];
                r[q * 4 + 0] = fmaxf(acc[q * 4 + 0] * aa.x + bb.x, 0.f);
                r[q * 4 + 1] = fmaxf(acc[q * 4 + 1] * aa.y + bb.y, 0.f);
                r[q * 4 + 2] = fmaxf(acc[q * 4 + 2] * aa.z + bb.z, 0.f);
                r[q * 4 + 3] = fmaxf(acc[q * 4 + 3] * aa.w + bb.w, 0.f);
            }
            float m = 0.f;
            #pragma unroll
            for (int j = 0; j < 8; ++j) m = fmaxf(m, r[j]);
            #pragma unroll
            for (int off = 1; off < 16; off <<= 1) m = fmaxf(m, __shfl_xor(m, off, 64));
            float inv = (m > 0.f) ? 127.0f / m : 0.f;
            uint2 pk;
            pk.x = packq(&r[0], inv);
            pk.y = packq(&r[4], inv);
            outq[(size_t)row * 16 + c] = pk;
            if (c == 0) osraw[row] = m * (1.0f / 127.0f);
        }
    }
}

// ---------------- SpMM layer 2: aggregate + bias + pooled-sum ----------------
__global__ __launch_bounds__(256) void k_spmm_pool(
    const uint2* __restrict__ xq, const int* __restrict__ perm, const int* __restrict__ offs,
    const int* __restrict__ deg, const float* __restrict__ dinv, const float* __restrict__ spre,
    const float* __restrict__ bias, const int* __restrict__ batch,
    float* __restrict__ psum, int* __restrict__ pcnt) {
    __shared__ float red[4][128];
    __shared__ int gid[4];
    int w = threadIdx.x >> 6;
    int lane = threadIdx.x & 63;
    int g = lane >> 4, c = lane & 15;
    int base = blockIdx.x * 64;
    for (int i = 0; i < 16; ++i) {
        int row = __builtin_amdgcn_readfirstlane(base + i * 4 + w);
        bool valid = row < N_NODES;
        SPMM_ROW_GATHER()
        if (g == 0) {
            int ch = c * 8;
            if (valid) {
                uint2 v = xq[(size_t)row * 16 + c];
                float fs = di * spre[row];
                ACCI8(fs, v)
                #pragma unroll
                for (int j = 0; j < 8; ++j) red[w][ch + j] = acc[j] + bias[ch + j];
            } else {
                #pragma unroll
                for (int j = 0; j < 8; ++j) red[w][ch + j] = 0.f;
            }
        }
        if (lane == 0) gid[w] = valid ? batch[row] : -1;
        __syncthreads();
        bool same = (gid[0] >= 0) && (gid[0] == gid[1]) && (gid[1] == gid[2]) && (gid[2] == gid[3]);
        int c0 = lane * 2;
        if (same) {
            if (w == 0) {
                float sx = red[0][c0] + red[1][c0] + red[2][c0] + red[3][c0];
                float sy = red[0][c0 + 1] + red[1][c0 + 1] + red[2][c0 + 1] + red[3][c0 + 1];
                unsafeAtomicAdd(&psum[gid[0] * CH + c0], sx);
                unsafeAtomicAdd(&psum[gid[0] * CH + c0 + 1], sy);
                if (lane == 0) atomicAdd(&pcnt[gid[0]], 4);
            }
        } else if (gid[w] >= 0) {
            unsafeAtomicAdd(&psum[gid[w] * CH + c0], red[w][c0]);
            unsafeAtomicAdd(&psum[gid[w] * CH + c0 + 1], red[w][c0 + 1]);
            if (lane == 0) atomicAdd(&pcnt[gid[w]], 1);
        }
        __syncthreads();
    }
}

// ---------------- head ----------------
__global__ __launch_bounds__(128) void k_head(const float* __restrict__ psum, const int* __restrict__ pcnt,
                                              const float* __restrict__ fw1, const float* __restrict__ fb1,
                                              const float* __restrict__ cw, const float* __restrict__ cb,
                                              float* __restrict__ out) {
    __shared__ float fws[128 * 64];
    for (int i = threadIdx.x; i < 128 * 64; i += 128) fws[i] = fw1[i];
    __syncthreads();
    int g = threadIdx.x;
    float z[64];
    #pragma unroll
    for (int j = 0; j < 64; ++j) z[j] = fb1[j];
    float cnt = fmaxf((float)pcnt[g], 1.f);
    float inv = 1.f / cnt;
    for (int c = 0; c < 128; ++c) {
        float p = psum[g * CH + c] * inv;
        #pragma unroll
        for (int j = 0; j < 64; ++j) z[j] += p * fws[c * 64 + j];
    }
    float o0 = cb[0], o1 = cb[1];
    #pragma unroll
    for (int j = 0; j < 64; ++j) {
        float zz = fmaxf(z[j], 0.f);
        o0 += zz * cw[j * 2];
        o1 += zz * cw[j * 2 + 1];
    }
    out[g * 2] = o0;
    out[g * 2 + 1] = o1;
}

extern "C" void kernel_launch(void* const* d_in, const int* in_sizes, int n_in,
                              void* d_out, int out_size, void* d_ws, size_t ws_size,
                              hipStream_t stream) {
    const float* x     = (const float*)d_in[0];
    const int*   ei    = (const int*)d_in[1];
    const int*   batch = (const int*)d_in[2];
    const float* W1    = (const float*)d_in[3];
    const float* b1    = (const float*)d_in[4];
    const float* gamma = (const float*)d_in[5];
    const float* beta  = (const float*)d_in[6];
    const float* rmean = (const float*)d_in[7];
    const float* rvar  = (const float*)d_in[8];
    const float* W2    = (const float*)d_in[9];
    const float* b2    = (const float*)d_in[10];
    const float* fw1   = (const float*)d_in[11];
    const float* fb1   = (const float*)d_in[12];
    const float* cw    = (const float*)d_in[13];
    const float* cb    = (const float*)d_in[14];
    const int* srcp = ei;
    const int* dstp = ei + N_EDGES;

    char* w = (char*)d_ws;
    // zeroed region first
    int*   bcnt  = (int*)w;   w += 4096;
    float* psum  = (float*)w; w += 65536;
    int*   pcnt  = (int*)w;   w += 512;
    size_t zbytes = 4096 + 65536 + 512;
    // non-zeroed
    int*   deg   = (int*)w;   w += 400000;
    int*   offs  = (int*)w;   w += 400000;
    float* dinv  = (float*)w; w += 400000;
    float* xsA   = (float*)w; w += 400000;
    float* spreA = (float*)w; w += 400000;
    float* srawB = (float*)w; w += 400000;
    float* spreC = (float*)w; w += 400000;
    float* A1    = (float*)w; w += 512;
    float* B1    = (float*)w; w += 512;
    float* wcs1  = (float*)w; w += 512;
    float* wcs2  = (float*)w; w += 512;
    unsigned char* Wq1T = (unsigned char*)w; w += 16384;
    unsigned char* Wq2T = (unsigned char*)w; w += 16384;
    int*   boffs = (int*)w;   w += 4096;
    int*   bcur  = (int*)w;   w += 4096;
    unsigned int* pairs = (unsigned int*)w; w += 12800000;
    int*   perm  = (int*)w;   w += 12800000;
    unsigned char* Xq   = (unsigned char*)w; w += 12800000;  // int8 [100k,128]
    unsigned char* bufA = (unsigned char*)w; w += 12800000;
    unsigned char* bufB = (unsigned char*)w; w += 12800000;
    unsigned char* bufC = (unsigned char*)w; w += 12800000;

    hipMemsetAsync(d_ws, 0, zbytes, stream);
    k_quantx<<<6250, 256, 0, stream>>>(x, Xq, xsA);
    k_bhist<<<200, 256, 0, stream>>>(dstp, bcnt);
    k_bscan<<<1, 256, 0, stream>>>(bcnt, boffs, bcur);
    k_bin<<<(N_EDGES + EPB - 1) / EPB, 256, 0, stream>>>(srcp, dstp, bcur, pairs);
    k_bfill<<<NBUCK, 256, 0, stream>>>(pairs, boffs, offs, deg, dinv, perm);
    k_prepW<<<1, 256, 0, stream>>>(W1, W2, gamma, beta, rmean, rvar, b1,
                                   Wq1T, wcs1, Wq2T, wcs2, A1, B1);
    k_gemm_mfma<<<1563, 256, 0, stream>>>(Xq, xsA, Wq1T, wcs1, dinv, bufA, spreA);
    k_spmm_bn_relu<<<NSPB, 256, 0, stream>>>((const uint2*)bufA, perm, offs, deg, dinv, spreA,
                                             A1, B1, (uint2*)bufB, srawB);
    k_gemm_mfma<<<1563, 256, 0, stream>>>(bufB, srawB, Wq2T, wcs2, dinv, bufC, spreC);
    k_spmm_pool<<<NSPB, 256, 0, stream>>>((const uint2*)bufC, perm, offs, deg, dinv, spreC,
                                          b2, batch, psum, pcnt);
    k_head<<<1, 128, 0, stream>>>(psum, pcnt, fw1, fb1, cw, cb, (float*)d_out);
}

// Round 8
// 518.203 us; speedup vs baseline: 11.0466x; 1.0716x over previous
//
#include <hip/hip_runtime.h>
#include <hip/hip_bf16.h>

#define N_NODES 100000
#define N_EDGES 3200000
#define CH 128
#define NG 128
#define BN_EPS 1e-5f
#define NBUCK 1024   // bucket = dst >> 7 (128 nodes per bucket)
#define EPB 16384    // edges per k_bin block
#define NSPB 1563    // spmm blocks: 64 rows each, co-resident grid

using i32x4 = __attribute__((ext_vector_type(4))) int;

__device__ __forceinline__ unsigned int packq(const float* v, float inv) {
    int q0 = __float2int_rn(v[0] * inv), q1 = __float2int_rn(v[1] * inv);
    int q2 = __float2int_rn(v[2] * inv), q3 = __float2int_rn(v[3] * inv);
    return (unsigned int)(q0 & 255) | ((unsigned int)(q1 & 255) << 8) |
           ((unsigned int)(q2 & 255) << 16) | ((unsigned int)(q3 & 255) << 24);
}

// ---------------- quantize W1/W2 per column (transposed) + BN fold ----------------
__global__ __launch_bounds__(256) void k_prepW(
    const float* __restrict__ W1, const float* __restrict__ W2,
    const float* __restrict__ gamma, const float* __restrict__ beta,
    const float* __restrict__ rmean, const float* __restrict__ rvar, const float* __restrict__ b1,
    unsigned char* __restrict__ Wq1T, float* __restrict__ wcs1,
    unsigned char* __restrict__ Wq2T, float* __restrict__ wcs2,
    float* __restrict__ A1, float* __restrict__ B1) {
    int t = threadIdx.x;
    const float* W = (t < 128) ? W1 : W2;
    unsigned char* WT = (t < 128) ? Wq1T : Wq2T;
    float* wcs = (t < 128) ? wcs1 : wcs2;
    int c = t & 127;
    float m = 0.f;
    for (int k = 0; k < 128; ++k) m = fmaxf(m, fabsf(W[k * CH + c]));
    float inv = (m > 0.f) ? 127.0f / m : 0.f;
    for (int k = 0; k < 128; ++k) {
        int q = __float2int_rn(W[k * CH + c] * inv);
        WT[c * CH + k] = (unsigned char)(q & 255);
    }
    wcs[c] = m * (1.0f / 127.0f);
    if (t < 128) {
        float a = gamma[c] * rsqrtf(rvar[c] + BN_EPS);
        A1[c] = a;
        B1[c] = (b1[c] - rmean[c]) * a + beta[c];
    }
}

// ---------------- bucket histogram ----------------
__global__ __launch_bounds__(256) void k_bhist(const int* __restrict__ dst, int* __restrict__ bcnt) {
    __shared__ int lh[NBUCK];
    for (int i = threadIdx.x; i < NBUCK; i += 256) lh[i] = 0;
    __syncthreads();
    for (int e = blockIdx.x * 256 + threadIdx.x; e < N_EDGES; e += gridDim.x * 256)
        atomicAdd(&lh[dst[e] >> 7], 1);
    __syncthreads();
    for (int i = threadIdx.x; i < NBUCK; i += 256) {
        int v = lh[i];
        if (v) atomicAdd(&bcnt[i], v);
    }
}

// ---------------- scan 1024 -> exclusive bases + cursor copy ----------------
__global__ __launch_bounds__(256) void k_bscan(const int* __restrict__ in, int* __restrict__ out,
                                               int* __restrict__ cur) {
    __shared__ int sm[256];
    int t = threadIdx.x;
    int4 v = *(const int4*)&in[t * 4];
    int tsum = v.x + v.y + v.z + v.w;
    sm[t] = tsum;
    __syncthreads();
    for (int off = 1; off < 256; off <<= 1) {
        int val = sm[t];
        int add = (t >= off) ? sm[t - off] : 0;
        __syncthreads();
        sm[t] = val + add;
        __syncthreads();
    }
    int excl = sm[t] - tsum;
    int o0 = excl, o1 = excl + v.x, o2 = o1 + v.y, o3 = o2 + v.z;
    out[t * 4] = o0; out[t * 4 + 1] = o1; out[t * 4 + 2] = o2; out[t * 4 + 3] = o3;
    if (cur) { cur[t * 4] = o0; cur[t * 4 + 1] = o1; cur[t * 4 + 2] = o2; cur[t * 4 + 3] = o3; }
}

// ---------------- bin edges into per-bucket packed segments ----------------
__global__ __launch_bounds__(256) void k_bin(const int* __restrict__ src, const int* __restrict__ dst,
                                             int* __restrict__ bcur, unsigned int* __restrict__ pairs) {
    __shared__ int lhist[NBUCK];
    __shared__ int lbase[NBUCK];
    int t = threadIdx.x;
    for (int i = t; i < NBUCK; i += 256) lhist[i] = 0;
    __syncthreads();
    int base = blockIdx.x * EPB;
    int lim = min(base + EPB, N_EDGES);
    for (int e = base + t; e < lim; e += 256)
        atomicAdd(&lhist[dst[e] >> 7], 1);
    __syncthreads();
    for (int i = t; i < NBUCK; i += 256) {
        int h = lhist[i];
        lbase[i] = h ? atomicAdd(&bcur[i], h) : 0;
        lhist[i] = 0;
    }
    __syncthreads();
    for (int e = base + t; e < lim; e += 256) {
        int d = dst[e];
        int b = d >> 7;
        int r = atomicAdd(&lhist[b], 1);
        pairs[lbase[b] + r] = ((unsigned int)src[e] << 7) | ((unsigned int)d & 127u);
    }
}

// ---------------- per-bucket CSR fill + deg/offs/dinv, src-octant ordered ----------------
__global__ __launch_bounds__(256) void k_bfill(const unsigned int* __restrict__ pairs,
                                               const int* __restrict__ boffs,
                                               int* __restrict__ offs, int* __restrict__ deg,
                                               float* __restrict__ dinv, int* __restrict__ perm) {
    __shared__ int lcur[1024];
    __shared__ int loff[1024];
    __shared__ int sm[256];
    int b = blockIdx.x;
    int t = threadIdx.x;
    for (int i = t; i < 1024; i += 256) lcur[i] = 0;
    __syncthreads();
    int p0 = boffs[b];
    int p1 = (b == NBUCK - 1) ? N_EDGES : boffs[b + 1];
    for (int p = p0 + t; p < p1; p += 256) {
        unsigned int e = pairs[p];
        int idx = (int)((e & 127u) << 3) | (int)((e >> 7) >> 14);
        atomicAdd(&lcur[idx], 1);
    }
    __syncthreads();
    int4 v = *(const int4*)&lcur[t * 4];
    int tsum = v.x + v.y + v.z + v.w;
    sm[t] = tsum;
    __syncthreads();
    for (int off = 1; off < 256; off <<= 1) {
        int val = sm[t];
        int add = (t >= off) ? sm[t - off] : 0;
        __syncthreads();
        sm[t] = val + add;
        __syncthreads();
    }
    int excl = sm[t] - tsum + p0;
    loff[t * 4]     = excl;
    loff[t * 4 + 1] = excl + v.x;
    loff[t * 4 + 2] = excl + v.x + v.y;
    loff[t * 4 + 3] = excl + v.x + v.y + v.z;
    lcur[t * 4] = 0; lcur[t * 4 + 1] = 0; lcur[t * 4 + 2] = 0; lcur[t * 4 + 3] = 0;
    __syncthreads();
    if (t < 128) {
        int node = (b << 7) + t;
        if (node < N_NODES) {
            int o0 = loff[t * 8];
            int o1 = (t == 127) ? p1 : loff[(t + 1) * 8];
            int cnt = o1 - o0;
            offs[node] = o0;
            deg[node] = cnt;
            dinv[node] = rsqrtf((float)(cnt + 1));
        }
    }
    __syncthreads();
    for (int p = p0 + t; p < p1; p += 256) {
        unsigned int e = pairs[p];
        int src = (int)(e >> 7);
        int idx = (int)((e & 127u) << 3) | (src >> 14);
        int r = atomicAdd(&lcur[idx], 1);
        perm[loff[idx] + r] = src;
    }
}

// ---------------- fused GEMM layer1: f32 input, in-register row quant + MFMA ----------------
// Replaces k_quantx + int8-input GEMM: removes the 25.6MB Xq round-trip + a launch.
__global__ __launch_bounds__(256) void k_gemm_f32(
    const float* __restrict__ X,
    const unsigned char* __restrict__ WT, const float* __restrict__ wcs,
    const float* __restrict__ dinvp, unsigned char* __restrict__ Yq, float* __restrict__ ospre) {
    __shared__ float ep[4][16][132];
    int t = threadIdx.x;
    int w = t >> 6;
    int lane = t & 63;
    int quad = lane >> 4, l16 = lane & 15;
    int row0 = blockIdx.x * 64 + w * 16;

    int arow = row0 + l16;
    if (arow >= N_NODES) arow = N_NODES - 1;

    float xv[32];
    {
        const float4* p0 = (const float4*)&X[(size_t)arow * CH + quad * 16];
        const float4* p1 = (const float4*)&X[(size_t)arow * CH + 64 + quad * 16];
        #pragma unroll
        for (int q = 0; q < 4; ++q) {
            float4 f = p0[q];
            xv[q * 4 + 0] = f.x; xv[q * 4 + 1] = f.y; xv[q * 4 + 2] = f.z; xv[q * 4 + 3] = f.w;
        }
        #pragma unroll
        for (int q = 0; q < 4; ++q) {
            float4 f = p1[q];
            xv[16 + q * 4 + 0] = f.x; xv[16 + q * 4 + 1] = f.y;
            xv[16 + q * 4 + 2] = f.z; xv[16 + q * 4 + 3] = f.w;
        }
    }
    // row max across the 4 quads holding this row
    float m = 0.f;
    #pragma unroll
    for (int j = 0; j < 32; ++j) m = fmaxf(m, fabsf(xv[j]));
    m = fmaxf(m, __shfl_xor(m, 16, 64));
    m = fmaxf(m, __shfl_xor(m, 32, 64));
    float inv = (m > 0.f) ? 127.0f / m : 0.f;
    float ms = m * (1.0f / 127.0f);
    unsigned int pk[8];
    #pragma unroll
    for (int j = 0; j < 8; ++j) pk[j] = packq(&xv[j * 4], inv);
    i32x4 a0 = (i32x4){(int)pk[0], (int)pk[1], (int)pk[2], (int)pk[3]};
    i32x4 a1 = (i32x4){(int)pk[4], (int)pk[5], (int)pk[6], (int)pk[7]};

    i32x4 acc[8];
    #pragma unroll
    for (int i = 0; i < 8; ++i) acc[i] = (i32x4){0, 0, 0, 0};
    #pragma unroll
    for (int tt = 0; tt < 8; ++tt) {
        int n = tt * 16 + l16;
        i32x4 b0 = *(const i32x4*)&WT[(size_t)n * CH + quad * 16];
        i32x4 b1 = *(const i32x4*)&WT[(size_t)n * CH + 64 + quad * 16];
        acc[tt] = __builtin_amdgcn_mfma_i32_16x16x64_i8(a0, b0, acc[tt], 0, 0, 0);
        acc[tt] = __builtin_amdgcn_mfma_i32_16x16x64_i8(a1, b1, acc[tt], 0, 0, 0);
    }

    // xs of rows quad*4+r live in lanes l16==quad*4+r (quad 0 copy = lanes 0..15)
    float xsr[4];
    #pragma unroll
    for (int r = 0; r < 4; ++r) xsr[r] = __shfl(ms, quad * 4 + r, 64);
    #pragma unroll
    for (int tt = 0; tt < 8; ++tt) {
        float wc = wcs[tt * 16 + l16];
        #pragma unroll
        for (int r = 0; r < 4; ++r)
            ep[w][quad * 4 + r][tt * 16 + l16] = (float)acc[tt][r] * xsr[r] * wc;
    }
    __syncthreads();

    int rl = lane >> 2, part = lane & 3;
    int grow = row0 + rl;
    float v[32];
    float mm = 0.f;
    #pragma unroll
    for (int i = 0; i < 32; ++i) {
        v[i] = ep[w][rl][part * 32 + i];
        mm = fmaxf(mm, fabsf(v[i]));
    }
    mm = fmaxf(mm, __shfl_xor(mm, 1, 64));
    mm = fmaxf(mm, __shfl_xor(mm, 2, 64));
    if (grow < N_NODES) {
        float inv2 = (mm > 0.f) ? 127.0f / mm : 0.f;
        unsigned int o[8];
        #pragma unroll
        for (int q = 0; q < 8; ++q) o[q] = packq(&v[q * 4], inv2);
        uint4* dst0 = (uint4*)&Yq[(size_t)grow * CH + part * 32];
        dst0[0] = make_uint4(o[0], o[1], o[2], o[3]);
        dst0[1] = make_uint4(o[4], o[5], o[6], o[7]);
        if (part == 0) ospre[grow] = (mm * (1.0f / 127.0f)) * dinvp[grow];
    }
}

// ---------------- int8-input GEMM (layer 2) ----------------
__global__ __launch_bounds__(256) void k_gemm_mfma(
    const unsigned char* __restrict__ Xq, const float* __restrict__ xs,
    const unsigned char* __restrict__ WT, const float* __restrict__ wcs,
    const float* __restrict__ dinvp, unsigned char* __restrict__ Yq, float* __restrict__ ospre) {
    __shared__ float ep[4][16][132];
    int t = threadIdx.x;
    int w = t >> 6;
    int lane = t & 63;
    int quad = lane >> 4, l16 = lane & 15;
    int row0 = blockIdx.x * 64 + w * 16;

    int arow = row0 + l16;
    if (arow >= N_NODES) arow = N_NODES - 1;
    i32x4 a0 = *(const i32x4*)&Xq[(size_t)arow * CH + quad * 16];
    i32x4 a1 = *(const i32x4*)&Xq[(size_t)arow * CH + 64 + quad * 16];

    i32x4 acc[8];
    #pragma unroll
    for (int i = 0; i < 8; ++i) acc[i] = (i32x4){0, 0, 0, 0};

    #pragma unroll
    for (int tt = 0; tt < 8; ++tt) {
        int n = tt * 16 + l16;
        i32x4 b0 = *(const i32x4*)&WT[(size_t)n * CH + quad * 16];
        i32x4 b1 = *(const i32x4*)&WT[(size_t)n * CH + 64 + quad * 16];
        acc[tt] = __builtin_amdgcn_mfma_i32_16x16x64_i8(a0, b0, acc[tt], 0, 0, 0);
        acc[tt] = __builtin_amdgcn_mfma_i32_16x16x64_i8(a1, b1, acc[tt], 0, 0, 0);
    }

    float xsr[4];
    #pragma unroll
    for (int r = 0; r < 4; ++r) {
        int rr = row0 + quad * 4 + r;
        xsr[r] = xs[(rr < N_NODES) ? rr : (N_NODES - 1)];
    }
    #pragma unroll
    for (int tt = 0; tt < 8; ++tt) {
        float wc = wcs[tt * 16 + l16];
        #pragma unroll
        for (int r = 0; r < 4; ++r)
            ep[w][quad * 4 + r][tt * 16 + l16] = (float)acc[tt][r] * xsr[r] * wc;
    }
    __syncthreads();

    int rl = lane >> 2, part = lane & 3;
    int grow = row0 + rl;
    float v[32];
    float m = 0.f;
    #pragma unroll
    for (int i = 0; i < 32; ++i) {
        v[i] = ep[w][rl][part * 32 + i];
        m = fmaxf(m, fabsf(v[i]));
    }
    m = fmaxf(m, __shfl_xor(m, 1, 64));
    m = fmaxf(m, __shfl_xor(m, 2, 64));
    if (grow < N_NODES) {
        float inv = (m > 0.f) ? 127.0f / m : 0.f;
        unsigned int o[8];
        #pragma unroll
        for (int q = 0; q < 8; ++q) o[q] = packq(&v[q * 4], inv);
        uint4* dst0 = (uint4*)&Yq[(size_t)grow * CH + part * 32];
        dst0[0] = make_uint4(o[0], o[1], o[2], o[3]);
        dst0[1] = make_uint4(o[4], o[5], o[6], o[7]);
        if (part == 0) ospre[grow] = (m * (1.0f / 127.0f)) * dinvp[grow];
    }
}

// ---------------- SpMM v8: pair-of-rows interleaved chunk-4 sorted walk ----------------
// Two rows advance through their class-sorted edge lists in lockstep with chunk 4
// each: 8 lines in flight per wave-iter (same MLP as R7) but each row's chunk spans
// only 1/8 of its sorted src range -> in-flight address zone ~1.6MB (was 3.2MB).
#define ACCI8P(acc, f, v)                                                              \
    { int _a = (int)v.x, _b = (int)v.y;                                                \
      acc[0] += f * (float)((_a << 24) >> 24);                                         \
      acc[1] += f * (float)((_a << 16) >> 24);                                         \
      acc[2] += f * (float)((_a << 8) >> 24);                                          \
      acc[3] += f * (float)(_a >> 24);                                                 \
      acc[4] += f * (float)((_b << 24) >> 24);                                         \
      acc[5] += f * (float)((_b << 16) >> 24);                                         \
      acc[6] += f * (float)((_b << 8) >> 24);                                          \
      acc[7] += f * (float)(_b >> 24); }

#define SPMM_PAIR_GATHER(ii)                                                           \
    int rowA = __builtin_amdgcn_readfirstlane(base + (ii) * 4 + w);                    \
    int rowB = __builtin_amdgcn_readfirstlane(base + (ii) * 4 + 4 + w);                \
    bool valA = rowA < N_NODES, valB = rowB < N_NODES;                                 \
    float diA = 0.f, diB = 0.f;                                                        \
    int begA = 0, endA = 0, begB = 0, endB = 0;                                        \
    if (valA) { diA = dinv[rowA]; begA = offs[rowA]; endA = begA + deg[rowA]; }        \
    if (valB) { diB = dinv[rowB]; begB = offs[rowB]; endB = begB + deg[rowB]; }        \
    float accA[8], accB[8];                                                            \
    _Pragma("unroll") for (int j = 0; j < 8; ++j) { accA[j] = 0.f; accB[j] = 0.f; }    \
    int cbA = begA, cbB = begB;                                                        \
    while (cbA < endA || cbB < endB) {                                                 \
        int kA = cbA + g, kB = cbB + g;                                                \
        int kaA = (kA < endA) ? kA : ((endA > 1) ? endA - 1 : 0);                      \
        int kaB = (kB < endB) ? kB : ((endB > 1) ? endB - 1 : 0);                      \
        int sA = perm[kaA], sB = perm[kaB];                                            \
        float fA = (kA < endA) ? diA : 0.f;                                            \
        float fB = (kB < endB) ? diB : 0.f;                                            \
        fA *= spre[sA]; fB *= spre[sB];                                                \
        uint2 vA = xq[(size_t)sA * 16 + c];                                            \
        uint2 vB = xq[(size_t)sB * 16 + c];                                            \
        ACCI8P(accA, fA, vA) ACCI8P(accB, fB, vB)                                      \
        cbA += 4; cbB += 4;                                                            \
    }                                                                                  \
    _Pragma("unroll") for (int j = 0; j < 8; ++j) {                                    \
        accA[j] += __shfl_xor(accA[j], 16, 64);                                        \
        accA[j] += __shfl_xor(accA[j], 32, 64);                                        \
        accB[j] += __shfl_xor(accB[j], 16, 64);                                        \
        accB[j] += __shfl_xor(accB[j], 32, 64);                                        \
    }

__device__ __forceinline__ void bn_epi(int row, float di, float* acc, int c,
                                       const uint2* __restrict__ xq, const float* __restrict__ spre,
                                       const float* __restrict__ A1, const float* __restrict__ B1,
                                       uint2* __restrict__ outq, float* __restrict__ osraw) {
    uint2 v = xq[(size_t)row * 16 + c];
    float fs = di * spre[row];
    ACCI8P(acc, fs, v)
    int ch = c * 8;
    float r[8];
    const float4* A4 = (const float4*)&A1[ch];
    const float4* B4 = (const float4*)&B1[ch];
    #pragma unroll
    for (int q = 0; q < 2; ++q) {
        float4 aa = A4[q], bb = B4[q];
        r[q * 4 + 0] = fmaxf(acc[q * 4 + 0] * aa.x + bb.x, 0.f);
        r[q * 4 + 1] = fmaxf(acc[q * 4 + 1] * aa.y + bb.y, 0.f);
        r[q * 4 + 2] = fmaxf(acc[q * 4 + 2] * aa.z + bb.z, 0.f);
        r[q * 4 + 3] = fmaxf(acc[q * 4 + 3] * aa.w + bb.w, 0.f);
    }
    float m = 0.f;
    #pragma unroll
    for (int i = 0; i < 8; ++i) m = fmaxf(m, r[i]);
    #pragma unroll
    for (int off = 1; off < 16; off <<= 1) m = fmaxf(m, __shfl_xor(m, off, 64));
    float inv = (m > 0.f) ? 127.0f / m : 0.f;
    uint2 pk;
    pk.x = packq(&r[0], inv);
    pk.y = packq(&r[4], inv);
    outq[(size_t)row * 16 + c] = pk;
    if (c == 0) osraw[row] = m * (1.0f / 127.0f);
}

__device__ __forceinline__ void pool_epi(int row, bool valid, float di, float* acc,
                                         int w, int lane, int g, int c,
                                         const uint2* __restrict__ xq, const float* __restrict__ spre,
                                         const float* __restrict__ bias, const int* __restrict__ batch,
                                         float* __restrict__ psum, int* __restrict__ pcnt,
                                         float (*red)[128], int* gid) {
    if (g == 0) {
        int ch = c * 8;
        if (valid) {
            uint2 v = xq[(size_t)row * 16 + c];
            float fs = di * spre[row];
            ACCI8P(acc, fs, v)
            #pragma unroll
            for (int j = 0; j < 8; ++j) red[w][ch + j] = acc[j] + bias[ch + j];
        } else {
            #pragma unroll
            for (int j = 0; j < 8; ++j) red[w][ch + j] = 0.f;
        }
    }
    if (lane == 0) gid[w] = valid ? batch[row] : -1;
    __syncthreads();
    bool same = (gid[0] >= 0) && (gid[0] == gid[1]) && (gid[1] == gid[2]) && (gid[2] == gid[3]);
    int c0 = lane * 2;
    if (same) {
        if (w == 0) {
            float sx = red[0][c0] + red[1][c0] + red[2][c0] + red[3][c0];
            float sy = red[0][c0 + 1] + red[1][c0 + 1] + red[2][c0 + 1] + red[3][c0 + 1];
            unsafeAtomicAdd(&psum[gid[0] * CH + c0], sx);
            unsafeAtomicAdd(&psum[gid[0] * CH + c0 + 1], sy);
            if (lane == 0) atomicAdd(&pcnt[gid[0]], 4);
        }
    } else if (gid[w] >= 0) {
        unsafeAtomicAdd(&psum[gid[w] * CH + c0], red[w][c0]);
        unsafeAtomicAdd(&psum[gid[w] * CH + c0 + 1], red[w][c0 + 1]);
        if (lane == 0) atomicAdd(&pcnt[gid[w]], 1);
    }
    __syncthreads();
}

// ---------------- SpMM layer 1: aggregate + folded BN/ReLU -> int8 + raw scale ----------------
__global__ __launch_bounds__(256) void k_spmm_bn_relu(
    const uint2* __restrict__ xq, const int* __restrict__ perm, const int* __restrict__ offs,
    const int* __restrict__ deg, const float* __restrict__ dinv, const float* __restrict__ spre,
    const float* __restrict__ A1, const float* __restrict__ B1,
    uint2* __restrict__ outq, float* __restrict__ osraw) {
    int w = threadIdx.x >> 6;
    int lane = threadIdx.x & 63;
    int g = lane >> 4, c = lane & 15;
    int base = blockIdx.x * 64;
    for (int i = 0; i < 16; i += 2) {
        SPMM_PAIR_GATHER(i)
        if (g == 0 && valA) bn_epi(rowA, diA, accA, c, xq, spre, A1, B1, outq, osraw);
        if (g == 0 && valB) bn_epi(rowB, diB, accB, c, xq, spre, A1, B1, outq, osraw);
    }
}

// ---------------- SpMM layer 2: aggregate + bias + pooled-sum ----------------
__global__ __launch_bounds__(256) void k_spmm_pool(
    const uint2* __restrict__ xq, const int* __restrict__ perm, const int* __restrict__ offs,
    const int* __restrict__ deg, const float* __restrict__ dinv, const float* __restrict__ spre,
    const float* __restrict__ bias, const int* __restrict__ batch,
    float* __restrict__ psum, int* __restrict__ pcnt) {
    __shared__ float red[4][128];
    __shared__ int gid[4];
    int w = threadIdx.x >> 6;
    int lane = threadIdx.x & 63;
    int g = lane >> 4, c = lane & 15;
    int base = blockIdx.x * 64;
    for (int i = 0; i < 16; i += 2) {
        SPMM_PAIR_GATHER(i)
        pool_epi(rowA, valA, diA, accA, w, lane, g, c, xq, spre, bias, batch, psum, pcnt, red, gid);
        pool_epi(rowB, valB, diB, accB, w, lane, g, c, xq, spre, bias, batch, psum, pcnt, red, gid);
    }
}

// ---------------- head ----------------
__global__ __launch_bounds__(128) void k_head(const float* __restrict__ psum, const int* __restrict__ pcnt,
                                              const float* __restrict__ fw1, const float* __restrict__ fb1,
                                              const float* __restrict__ cw, const float* __restrict__ cb,
                                              float* __restrict__ out) {
    __shared__ float fws[128 * 64];
    for (int i = threadIdx.x; i < 128 * 64; i += 128) fws[i] = fw1[i];
    __syncthreads();
    int g = threadIdx.x;
    float z[64];
    #pragma unroll
    for (int j = 0; j < 64; ++j) z[j] = fb1[j];
    float cnt = fmaxf((float)pcnt[g], 1.f);
    float inv = 1.f / cnt;
    for (int c = 0; c < 128; ++c) {
        float p = psum[g * CH + c] * inv;
        #pragma unroll
        for (int j = 0; j < 64; ++j) z[j] += p * fws[c * 64 + j];
    }
    float o0 = cb[0], o1 = cb[1];
    #pragma unroll
    for (int j = 0; j < 64; ++j) {
        float zz = fmaxf(z[j], 0.f);
        o0 += zz * cw[j * 2];
        o1 += zz * cw[j * 2 + 1];
    }
    out[g * 2] = o0;
    out[g * 2 + 1] = o1;
}

extern "C" void kernel_launch(void* const* d_in, const int* in_sizes, int n_in,
                              void* d_out, int out_size, void* d_ws, size_t ws_size,
                              hipStream_t stream) {
    const float* x     = (const float*)d_in[0];
    const int*   ei    = (const int*)d_in[1];
    const int*   batch = (const int*)d_in[2];
    const float* W1    = (const float*)d_in[3];
    const float* b1    = (const float*)d_in[4];
    const float* gamma = (const float*)d_in[5];
    const float* beta  = (const float*)d_in[6];
    const float* rmean = (const float*)d_in[7];
    const float* rvar  = (const float*)d_in[8];
    const float* W2    = (const float*)d_in[9];
    const float* b2    = (const float*)d_in[10];
    const float* fw1   = (const float*)d_in[11];
    const float* fb1   = (const float*)d_in[12];
    const float* cw    = (const float*)d_in[13];
    const float* cb    = (const float*)d_in[14];
    const int* srcp = ei;
    const int* dstp = ei + N_EDGES;

    char* w = (char*)d_ws;
    // zeroed region first
    int*   bcnt  = (int*)w;   w += 4096;
    float* psum  = (float*)w; w += 65536;
    int*   pcnt  = (int*)w;   w += 512;
    size_t zbytes = 4096 + 65536 + 512;
    // non-zeroed
    int*   deg   = (int*)w;   w += 400000;
    int*   offs  = (int*)w;   w += 400000;
    float* dinv  = (float*)w; w += 400000;
    float* spreA = (float*)w; w += 400000;
    float* srawB = (float*)w; w += 400000;
    float* spreC = (float*)w; w += 400000;
    float* A1    = (float*)w; w += 512;
    float* B1    = (float*)w; w += 512;
    float* wcs1  = (float*)w; w += 512;
    float* wcs2  = (float*)w; w += 512;
    unsigned char* Wq1T = (unsigned char*)w; w += 16384;
    unsigned char* Wq2T = (unsigned char*)w; w += 16384;
    int*   boffs = (int*)w;   w += 4096;
    int*   bcur  = (int*)w;   w += 4096;
    unsigned int* pairs = (unsigned int*)w; w += 12800000;
    int*   perm  = (int*)w;   w += 12800000;
    unsigned char* bufA = (unsigned char*)w; w += 12800000;
    unsigned char* bufB = (unsigned char*)w; w += 12800000;
    unsigned char* bufC = (unsigned char*)w; w += 12800000;

    hipMemsetAsync(d_ws, 0, zbytes, stream);
    k_bhist<<<200, 256, 0, stream>>>(dstp, bcnt);
    k_bscan<<<1, 256, 0, stream>>>(bcnt, boffs, bcur);
    k_bin<<<(N_EDGES + EPB - 1) / EPB, 256, 0, stream>>>(srcp, dstp, bcur, pairs);
    k_bfill<<<NBUCK, 256, 0, stream>>>(pairs, boffs, offs, deg, dinv, perm);
    k_prepW<<<1, 256, 0, stream>>>(W1, W2, gamma, beta, rmean, rvar, b1,
                                   Wq1T, wcs1, Wq2T, wcs2, A1, B1);
    k_gemm_f32<<<1563, 256, 0, stream>>>(x, Wq1T, wcs1, dinv, bufA, spreA);
    k_spmm_bn_relu<<<NSPB, 256, 0, stream>>>((const uint2*)bufA, perm, offs, deg, dinv, spreA,
                                             A1, B1, (uint2*)bufB, srawB);
    k_gemm_mfma<<<1563, 256, 0, stream>>>(bufB, srawB, Wq2T, wcs2, dinv, bufC, spreC);
    k_spmm_pool<<<NSPB, 256, 0, stream>>>((const uint2*)bufC, perm, offs, deg, dinv, spreC,
                                          b2, batch, psum, pcnt);
    k_head<<<1, 128, 0, stream>>>(psum, pcnt, fw1, fb1, cw, cb, (float*)d_out);
}